// Round 18
// baseline (645.116 us; speedup 1.0000x reference)
//
#include <hip/hip_runtime.h>
#include <hip/hip_bf16.h>

// ======== d_ws byte offsets ========
#define WS_SUMS  0          // 5 zones x {sum,sumsq} f64 (512 doubles); zeroed by ae9_prep each launch
#define WS_W1T   4096       // 256 f32
#define WS_W2T   8192       // 8192 f32 -> 40960
#define WS_W3T   40960      // 1024 f32
#define WS_DW1T  45056      // 1024 f32
#define WS_DT1T  49152      // 8192 f32 -> 81920
#define WS_DT2T  81920      // 8192 f32 (padded co-stride 32) -> 114688
#define WS_E2F   114688     // 512 f32 -> 116736
#define WS_Y1    1048576    // f32 (32,16,128,128) 33,554,432 B ; dead after conv2
#define WS_Y5    1048576    // f32 (32,16,128,128) reuses Y1 slot ; dead after dect2

#define SUM1 0
#define SUM2 512
#define SUM3 1024
#define SUM4 1536
#define SUM5 2048

// ======== d_out FLOAT32 element offsets ========
#define OUT_XT 0
#define OUT_ZE 62914560
#define OUT_ZQ 67108864
#define OUT_LT 71303168

// ======== scratch inside d_out's x_tilde byte range ========
#define DO_Y2 0            // f32 (32,32,64,64) ; dead after conv3
#define DO_Y3 16777216     // f32 (32,32,64,64) ; dead after vq
#define DO_Y4 33554432     // f32 (32,32,64,64) ; dead after dect1

__device__ __forceinline__ double ae9_wsumd(double v){
  #pragma unroll
  for (int off = 32; off; off >>= 1) v += __shfl_xor(v, off);
  return v;
}

template<int C>
__device__ __forceinline__ void ae9_statsf(const float* a, double* red, double* gsum){
  const int lane = threadIdx.x & 63, wid = threadIdx.x >> 6;
  #pragma unroll
  for (int c = 0; c < C; ++c){
    double av = (double)a[c];
    double s = ae9_wsumd(av);
    double q = ae9_wsumd(av*av);
    if (lane == 0){ red[(wid*C + c)*2] = s; red[(wid*C + c)*2 + 1] = q; }
  }
  __syncthreads();
  if ((int)threadIdx.x < C){
    double s = 0.0, q = 0.0;
    #pragma unroll
    for (int wv = 0; wv < 4; ++wv){ s += red[(wv*C + threadIdx.x)*2]; q += red[(wv*C + threadIdx.x)*2 + 1]; }
    atomicAdd(&gsum[2*threadIdx.x],     s);
    atomicAdd(&gsum[2*threadIdx.x + 1], q);
  }
}

template<int C>
__device__ __forceinline__ void ae9_bnparams(float* pm, float* pr, float* pg, float* pb,
                                             const double* sums, const float* g, const float* be, double inv){
  if ((int)threadIdx.x < C){
    int c = threadIdx.x;
    double md = sums[2*c] * inv;
    double vd = sums[2*c+1] * inv - md*md;
    pm[c] = (float)md;
    float vf = (float)vd;
    pr[c] = __fdiv_rn(1.f, __fsqrt_rn(__fadd_rn(vf, 1e-5f)));
    pg[c] = g[c];
    pb[c] = be[c];
  }
  __syncthreads();
}

__device__ __forceinline__ float ae9_bn(float x, float m, float g, float r, float b){
  return __fadd_rn(__fmul_rn(__fmul_rn(g, __fsub_rn(x, m)), r), b);
}
__device__ __forceinline__ float ae9_bnrelu(float x, float m, float g, float r, float b){
  return fmaxf(ae9_bn(x, m, g, r, b), 0.f);
}

__device__ __forceinline__ float ae9_np_pairwise32(const float* a){
  float r[8];
  #pragma unroll
  for (int j = 0; j < 8; ++j)
    r[j] = __fadd_rn(__fadd_rn(__fadd_rn(a[j], a[8+j]), a[16+j]), a[24+j]);
  return __fadd_rn(__fadd_rn(__fadd_rn(r[0], r[1]), __fadd_rn(r[2], r[3])),
                   __fadd_rn(__fadd_rn(r[4], r[5]), __fadd_rn(r[6], r[7])));
}

// ---------- prep (now also zeroes the 512-double sums block) ----------
__global__ void ae9_prep(const float* __restrict__ w1, const float* __restrict__ w2,
                         const float* __restrict__ w3, const float* __restrict__ dw1,
                         const float* __restrict__ dtw1, const float* __restrict__ dtw2,
                         const float* __restrict__ emb, char* __restrict__ wsb){
  const int t = threadIdx.x;
  double* sums = (double*)(wsb + WS_SUMS);
  sums[t] = 0.0;
  sums[t + 256] = 0.0;
  float* w1T  = (float*)(wsb + WS_W1T);
  float* w2T  = (float*)(wsb + WS_W2T);
  float* w3T  = (float*)(wsb + WS_W3T);
  float* dw1T = (float*)(wsb + WS_DW1T);
  float* dt1T = (float*)(wsb + WS_DT1T);
  float* dt2T = (float*)(wsb + WS_DT2T);
  float* e2f  = (float*)(wsb + WS_E2F);
  if (t < 256) w1T[t] = w1[(t & 15)*16 + (t >> 4)];
  for (int i = t; i < 8192; i += 256){
    int co = i & 31, k = i >> 5;
    w2T[i] = w2[co*256 + k];
  }
  for (int i = t; i < 1024; i += 256){ int co = i & 31, ci = i >> 5; w3T[i]  = w3[co*32 + ci]; }
  for (int i = t; i < 1024; i += 256){ int co = i & 31, ci = i >> 5; dw1T[i] = dw1[co*32 + ci]; }
  for (int i = t; i < 8192; i += 256){
    int co = i & 15, ci = (i >> 4) & 31, tap = i >> 9;
    dt1T[i] = dtw1[(ci*16 + co)*16 + tap];
  }
  for (int i = t; i < 8192; i += 256){
    int co = i & 31; int r2 = i >> 5; int ci = r2 & 15; int tap = r2 >> 4;
    dt2T[i] = (co < 30) ? dtw2[(ci*30 + co)*16 + tap] : 0.f;
  }
  for (int k = t; k < 512; k += 256){
    float sq[32];
    #pragma unroll
    for (int c = 0; c < 32; ++c){ float e = emb[k*32 + c]; sq[c] = __fmul_rn(e, e); }
    e2f[k] = ae9_np_pairwise32(sq);
  }
}

// ---------- conv1 (UNCHANGED encoder) ----------
__global__ void __launch_bounds__(256) ae9_conv1(const float* __restrict__ x, const float* __restrict__ w1T,
                         const float* __restrict__ b1, float* __restrict__ y1, double* __restrict__ sums1){
  __shared__ double red[4*16*2];
  const int idx = blockIdx.x*256 + threadIdx.x;
  const int ox = idx & 127, oy = (idx >> 7) & 127, n = idx >> 14;
  float acc[16];
  #pragma unroll
  for (int c = 0; c < 16; ++c) acc[c] = 0.f;
  const float* xp = x + n*65536;
  for (int ky = 0; ky < 4; ++ky){
    int iy = 2*oy - 1 + ky;
    if (iy < 0 || iy >= 256) continue;
    for (int kx = 0; kx < 4; ++kx){
      int ix = 2*ox - 1 + kx;
      if (ix < 0 || ix >= 256) continue;
      float v = xp[iy*256 + ix];
      const float* w = w1T + (ky*4 + kx)*16;
      #pragma unroll
      for (int c = 0; c < 16; ++c) acc[c] = __fmaf_rn(v, w[c], acc[c]);
    }
  }
  float yv[16];
  float* yp = y1 + n*262144 + oy*128 + ox;
  #pragma unroll
  for (int c = 0; c < 16; ++c){ yv[c] = __fadd_rn(acc[c], b1[c]); yp[c*16384] = yv[c]; }
  ae9_statsf<16>(yv, red, sums1);
}

// ---------- conv2 (UNCHANGED encoder) ----------
__global__ void __launch_bounds__(256) ae9_conv2(const float* __restrict__ y1, const double* __restrict__ sums1,
                         const float* __restrict__ g1, const float* __restrict__ be1,
                         const float* __restrict__ w2T, const float* __restrict__ b2,
                         float* __restrict__ y2, double* __restrict__ sums2){
  __shared__ float pm[16], pr[16], pg[16], pb[16];
  __shared__ double red[4*32*2];
  ae9_bnparams<16>(pm, pr, pg, pb, sums1, g1, be1, 1.0/524288.0);
  const int idx = blockIdx.x*256 + threadIdx.x;
  const int ox = idx & 63, oy = (idx >> 6) & 63, n = idx >> 12;
  float acc[32];
  #pragma unroll
  for (int c = 0; c < 32; ++c) acc[c] = 0.f;
  const float* in = y1 + n*262144;
  for (int ci = 0; ci < 16; ++ci){
    const float m = pm[ci], g = pg[ci], r = pr[ci], b = pb[ci];
    const float* plane = in + ci*16384;
    for (int ky = 0; ky < 4; ++ky){
      int iy = 2*oy - 1 + ky;
      if (iy < 0 || iy >= 128) continue;
      for (int kx = 0; kx < 4; ++kx){
        int ix = 2*ox - 1 + kx;
        if (ix < 0 || ix >= 128) continue;
        float v = ae9_bnrelu(plane[iy*128 + ix], m, g, r, b);
        const float* w = w2T + (ci*16 + ky*4 + kx)*32;
        #pragma unroll
        for (int co = 0; co < 32; ++co) acc[co] = __fmaf_rn(v, w[co], acc[co]);
      }
    }
  }
  float yv[32];
  float* yp = y2 + n*131072 + oy*64 + ox;
  #pragma unroll
  for (int c = 0; c < 32; ++c){ yv[c] = __fadd_rn(acc[c], b2[c]); yp[c*4096] = yv[c]; }
  ae9_statsf<32>(yv, red, sums2);
}

// ---------- conv3 (UNCHANGED encoder) ----------
__global__ void __launch_bounds__(256) ae9_conv3(const float* __restrict__ y2, const double* __restrict__ sums2,
                         const float* __restrict__ g2, const float* __restrict__ be2,
                         const float* __restrict__ w3T, const float* __restrict__ b3,
                         float* __restrict__ y3, double* __restrict__ sums3){
  __shared__ float pm[32], pr[32], pg[32], pb[32];
  __shared__ double red[4*32*2];
  ae9_bnparams<32>(pm, pr, pg, pb, sums2, g2, be2, 1.0/131072.0);
  const int idx = blockIdx.x*256 + threadIdx.x;
  const int sp = idx & 4095, n = idx >> 12;
  const float* in = y2 + n*131072 + sp;
  float acc[32];
  #pragma unroll
  for (int c = 0; c < 32; ++c) acc[c] = 0.f;
  for (int ci = 0; ci < 32; ++ci){
    float v = ae9_bnrelu(in[ci*4096], pm[ci], pg[ci], pr[ci], pb[ci]);
    const float* w = w3T + ci*32;
    #pragma unroll
    for (int co = 0; co < 32; ++co) acc[co] = __fmaf_rn(v, w[co], acc[co]);
  }
  float yv[32];
  float* yp = y3 + n*131072 + sp;
  #pragma unroll
  for (int c = 0; c < 32; ++c){ yv[c] = __fadd_rn(acc[c], b3[c]); yp[c*4096] = yv[c]; }
  ae9_statsf<32>(yv, red, sums3);
}

// ---------- VQ v4 (unchanged from round 17): chunked LDS staging, full occupancy ----------
__global__ void __launch_bounds__(256) aeE_vq(const float* __restrict__ y3, const double* __restrict__ sums3,
                      const float* __restrict__ g3, const float* __restrict__ be3,
                      const float* __restrict__ emb, const float* __restrict__ e2f,
                      const float* __restrict__ dw1T, const float* __restrict__ db1,
                      float* __restrict__ y4, double* __restrict__ sums4,
                      float* __restrict__ out){
  __shared__ float pm[32], pr[32], pg[32], pb[32];
  __shared__ double red[4*32*2];
  __shared__ float embL[4096];                         // 128 codes x 32 = 16 KB
  ae9_bnparams<32>(pm, pr, pg, pb, sums3, g3, be3, 1.0/131072.0);
  const int idx = blockIdx.x*256 + threadIdx.x;        // 512 blocks x 256 px
  const int sp = idx & 4095, n = idx >> 12;
  const float* in = y3 + n*131072 + sp;
  float zf[32], z2q[32], zf2[32];
  #pragma unroll
  for (int c = 0; c < 32; ++c){
    zf[c]  = ae9_bn(in[c*4096], pm[c], pg[c], pr[c], pb[c]);
    z2q[c] = __fmul_rn(zf[c], zf[c]);
    zf2[c] = __fmul_rn(2.0f, zf[c]);
  }
  float* ze = out + OUT_ZE + n*131072 + sp;
  #pragma unroll
  for (int c = 0; c < 32; ++c) ze[c*4096] = zf[c];
  const float z2 = ae9_np_pairwise32(z2q);
  float best = 3.4e38f; int bi = 0;
  for (int c0 = 0; c0 < 512; c0 += 128){               // 4 ascending chunks
    __syncthreads();
    {
      const float4* src = reinterpret_cast<const float4*>(emb + c0*32);
      float4* dst = reinterpret_cast<float4*>(embL);
      for (int i = threadIdx.x; i < 1024; i += 256) dst[i] = src[i];
    }
    __syncthreads();
    for (int k = c0; k < c0 + 128; k += 8){            // identical per-k math, ascending scan
      float d8[8];
      #pragma unroll
      for (int j = 0; j < 8; ++j){
        const float* ek = embL + (k - c0 + j)*32;
        float acc = 0.f;
        #pragma unroll
        for (int c = 0; c < 32; ++c) acc = __fmaf_rn(zf2[c], ek[c], acc);
        float u = __fsub_rn(z2, acc);
        d8[j] = __fadd_rn(u, e2f[k + j]);
      }
      #pragma unroll
      for (int j = 0; j < 8; ++j)
        if (d8[j] < best){ best = d8[j]; bi = k + j; } // strict <, first-min
    }
  }
  out[OUT_LT + idx] = (float)bi;
  const float4* er = reinterpret_cast<const float4*>(emb + bi*32);
  float* zq = out + OUT_ZQ + n*131072 + sp;
  float acc[32];
  #pragma unroll
  for (int c = 0; c < 32; ++c) acc[c] = db1[c];
  #pragma unroll
  for (int j = 0; j < 8; ++j){
    float4 f = er[j];
    zq[(4*j+0)*4096] = f.x;
    zq[(4*j+1)*4096] = f.y;
    zq[(4*j+2)*4096] = f.z;
    zq[(4*j+3)*4096] = f.w;
    const float* w0 = dw1T + (4*j + 0)*32;
    const float* w1 = dw1T + (4*j + 1)*32;
    const float* w2 = dw1T + (4*j + 2)*32;
    const float* w3 = dw1T + (4*j + 3)*32;
    #pragma unroll
    for (int co = 0; co < 32; ++co){
      acc[co] = fmaf(f.x, w0[co], acc[co]);
      acc[co] = fmaf(f.y, w1[co], acc[co]);
      acc[co] = fmaf(f.z, w2[co], acc[co]);
      acc[co] = fmaf(f.w, w3[co], acc[co]);
    }
  }
  float* yp = y4 + n*131072 + sp;
  #pragma unroll
  for (int c = 0; c < 32; ++c) yp[c*4096] = acc[c];
  ae9_statsf<32>(acc, red, sums4);
}

// ---------- dect1 v3 (unchanged) ----------
__global__ void __launch_bounds__(256) aeB_dect1(const float* __restrict__ y4, const double* __restrict__ sums4,
                         const float* __restrict__ g4, const float* __restrict__ be4,
                         const float* __restrict__ wT, const float* __restrict__ bias,
                         float* __restrict__ y5, double* __restrict__ sums5){
  __shared__ float pm[32], pr[32], pg[32], pb[32];
  __shared__ double red[4*16*2];
  ae9_bnparams<32>(pm, pr, pg, pb, sums4, g4, be4, 1.0/131072.0);
  const int w = __builtin_amdgcn_readfirstlane(blockIdx.x*4 + (threadIdx.x >> 6));
  const int j = threadIdx.x & 63;
  const int p = w & 1, oy = (w >> 1) & 127, n = w >> 8;
  const int ky0 = (oy & 1) ? 0 : 1;
  float acc[16];
  #pragma unroll
  for (int c = 0; c < 16; ++c) acc[c] = bias[c];
  const float* in = y4 + n*131072;
  for (int ci = 0; ci < 32; ++ci){
    const float m = pm[ci], g = pg[ci], r = pr[ci], b = pb[ci];
    const float* plane = in + ci*4096;
    #pragma unroll
    for (int ty = 0; ty < 2; ++ty){
      const int ky = ky0 + 2*ty;
      const int iy = (oy + 1 - ky) >> 1;
      if (iy < 0 || iy >= 64) continue;
      const float* row = plane + iy*64;
      #pragma unroll
      for (int tx = 0; tx < 2; ++tx){
        const int kx = p ? 2*tx : 1 + 2*tx;
        const float4* wv = reinterpret_cast<const float4*>(wT + ((ky*4 + kx)*32 + ci)*16);
        float wgt[16];
        #pragma unroll
        for (int q = 0; q < 4; ++q) reinterpret_cast<float4*>(wgt)[q] = wv[q];
        int ix = j + p - tx;
        float v = (ix >= 0 && ix < 64) ? ae9_bnrelu(row[ix], m, g, r, b) : 0.f;
        #pragma unroll
        for (int co = 0; co < 16; ++co) acc[co] = fmaf(v, wgt[co], acc[co]);
      }
    }
  }
  float* op = y5 + ((size_t)n*16)*16384 + oy*128 + p;
  #pragma unroll
  for (int co = 0; co < 16; ++co) op[co*16384 + 2*j] = acc[co];
  ae9_statsf<16>(acc, red, sums5);
}

// ---------- dect2 v3 (unchanged) ----------
__global__ void __launch_bounds__(256) aeB_dect2(const float* __restrict__ y5, const double* __restrict__ sums5,
                         const float* __restrict__ g5, const float* __restrict__ be5,
                         const float* __restrict__ wT, const float* __restrict__ bias,
                         float* __restrict__ out){
  __shared__ float pm[16], pr[16], pg[16], pb[16];
  ae9_bnparams<16>(pm, pr, pg, pb, sums5, g5, be5, 1.0/524288.0);
  const int w = __builtin_amdgcn_readfirstlane(blockIdx.x*4 + (threadIdx.x >> 6));
  const int j = threadIdx.x & 63;
  const int p = w & 1, oy = (w >> 1) & 255, n = w >> 9;
  const int ky0 = (oy & 1) ? 0 : 1;
  float a0[30], a1[30];
  #pragma unroll
  for (int c = 0; c < 30; ++c){ a0[c] = bias[c]; a1[c] = bias[c]; }
  const float* in = y5 + n*262144;
  for (int ci = 0; ci < 16; ++ci){
    const float m = pm[ci], g = pg[ci], r = pr[ci], b = pb[ci];
    const float* plane = in + ci*16384;
    #pragma unroll
    for (int ty = 0; ty < 2; ++ty){
      const int ky = ky0 + 2*ty;
      const int iy = (oy + 1 - ky) >> 1;
      if (iy < 0 || iy >= 128) continue;
      const float* row = plane + iy*128;
      #pragma unroll
      for (int tx = 0; tx < 2; ++tx){
        const int kx = p ? 2*tx : 1 + 2*tx;
        const float4* wv = reinterpret_cast<const float4*>(wT + ((ky*4 + kx)*16 + ci)*32);
        float wgt[32];
        #pragma unroll
        for (int q = 0; q < 8; ++q) reinterpret_cast<float4*>(wgt)[q] = wv[q];
        int ix0 = j + p - tx;
        int ix1 = ix0 + 64;
        float v0 = (ix0 >= 0 && ix0 < 128) ? ae9_bnrelu(row[ix0], m, g, r, b) : 0.f;
        float v1 = (ix1 >= 0 && ix1 < 128) ? ae9_bnrelu(row[ix1], m, g, r, b) : 0.f;
        #pragma unroll
        for (int co = 0; co < 30; ++co){
          a0[co] = fmaf(v0, wgt[co], a0[co]);
          a1[co] = fmaf(v1, wgt[co], a1[co]);
        }
      }
    }
  }
  float* op = out + OUT_XT + ((size_t)n*30)*65536 + oy*256 + p;
  #pragma unroll
  for (int co = 0; co < 30; ++co){
    op[co*65536 + 2*j]        = a0[co];
    op[co*65536 + 2*(j + 64)] = a1[co];
  }
}

extern "C" void kernel_launch(void* const* d_in, const int* in_sizes, int n_in,
                              void* d_out, int out_size, void* d_ws, size_t ws_size,
                              hipStream_t stream) {
  const float* x    = (const float*)d_in[0];
  const float* w1   = (const float*)d_in[1];
  const float* b1   = (const float*)d_in[2];
  const float* g1   = (const float*)d_in[3];
  const float* be1  = (const float*)d_in[4];
  const float* w2   = (const float*)d_in[5];
  const float* b2   = (const float*)d_in[6];
  const float* g2   = (const float*)d_in[7];
  const float* be2  = (const float*)d_in[8];
  const float* w3   = (const float*)d_in[9];
  const float* b3   = (const float*)d_in[10];
  const float* g3   = (const float*)d_in[11];
  const float* be3  = (const float*)d_in[12];
  const float* emb  = (const float*)d_in[13];
  const float* dw1  = (const float*)d_in[14];
  const float* db1  = (const float*)d_in[15];
  const float* dg1  = (const float*)d_in[16];
  const float* dbe1 = (const float*)d_in[17];
  const float* dtw1 = (const float*)d_in[18];
  const float* dtb1 = (const float*)d_in[19];
  const float* dg2  = (const float*)d_in[20];
  const float* dbe2 = (const float*)d_in[21];
  const float* dtw2 = (const float*)d_in[22];
  const float* dtb2 = (const float*)d_in[23];

  char* wsb = (char*)d_ws;
  char* ob  = (char*)d_out;
  float* out = (float*)d_out;

  double* sums1 = (double*)(wsb + WS_SUMS + SUM1);
  double* sums2 = (double*)(wsb + WS_SUMS + SUM2);
  double* sums3 = (double*)(wsb + WS_SUMS + SUM3);
  double* sums4 = (double*)(wsb + WS_SUMS + SUM4);
  double* sums5 = (double*)(wsb + WS_SUMS + SUM5);
  float* y1 = (float*)(wsb + WS_Y1);
  float* y5 = (float*)(wsb + WS_Y5);
  float* y2 = (float*)(ob + DO_Y2);
  float* y3 = (float*)(ob + DO_Y3);
  float* y4 = (float*)(ob + DO_Y4);

  ae9_prep<<<1, 256, 0, stream>>>(w1, w2, w3, dw1, dtw1, dtw2, emb, wsb);
  ae9_conv1<<<2048, 256, 0, stream>>>(x, (const float*)(wsb + WS_W1T), b1, y1, sums1);
  ae9_conv2<<<512, 256, 0, stream>>>(y1, sums1, g1, be1, (const float*)(wsb + WS_W2T), b2, y2, sums2);
  ae9_conv3<<<512, 256, 0, stream>>>(y2, sums2, g2, be2, (const float*)(wsb + WS_W3T), b3, y3, sums3);
  aeE_vq<<<512, 256, 0, stream>>>(y3, sums3, g3, be3, emb, (const float*)(wsb + WS_E2F),
                                  (const float*)(wsb + WS_DW1T), db1, y4, sums4, out);
  aeB_dect1<<<2048, 256, 0, stream>>>(y4, sums4, dg1, dbe1, (const float*)(wsb + WS_DT1T), dtb1, y5, sums5);
  aeB_dect2<<<4096, 256, 0, stream>>>(y5, sums5, dg2, dbe2, (const float*)(wsb + WS_DT2T), dtb2, out);
}

// Round 19
// 595.045 us; speedup vs baseline: 1.0841x; 1.0841x over previous
//
#include <hip/hip_runtime.h>
#include <hip/hip_bf16.h>

// ======== d_ws byte offsets ========
#define WS_SUMS  0          // 5 zones x {sum,sumsq} f64 (512 doubles); zeroed by ae9_prep each launch
#define WS_W1T   4096       // 256 f32
#define WS_W2T   8192       // 8192 f32 -> 40960
#define WS_W3T   40960      // 1024 f32
#define WS_DW1T  45056      // 1024 f32
#define WS_DT1T  49152      // 8192 f32 -> 81920
#define WS_DT2T  81920      // 8192 f32 (padded co-stride 32) -> 114688
#define WS_E2F   114688     // 512 f32 -> 116736
#define WS_Y1    1048576    // f32 (32,16,128,128) 33,554,432 B ; dead after conv2
#define WS_Y5    1048576    // f32 (32,16,128,128) reuses Y1 slot ; dead after dect2

#define SUM1 0
#define SUM2 512
#define SUM3 1024
#define SUM4 1536
#define SUM5 2048

// ======== d_out FLOAT32 element offsets ========
#define OUT_XT 0
#define OUT_ZE 62914560
#define OUT_ZQ 67108864
#define OUT_LT 71303168

// ======== scratch inside d_out's x_tilde byte range ========
#define DO_Y2 0            // f32 (32,32,64,64) ; dead after conv3
#define DO_Y3 16777216     // f32 (32,32,64,64) ; dead after vq
#define DO_Y4 33554432     // f32 (32,32,64,64) ; dead after dect1

__device__ __forceinline__ double ae9_wsumd(double v){
  #pragma unroll
  for (int off = 32; off; off >>= 1) v += __shfl_xor(v, off);
  return v;
}

template<int C>
__device__ __forceinline__ void ae9_statsf(const float* a, double* red, double* gsum){
  const int lane = threadIdx.x & 63, wid = threadIdx.x >> 6;
  #pragma unroll
  for (int c = 0; c < C; ++c){
    double av = (double)a[c];
    double s = ae9_wsumd(av);
    double q = ae9_wsumd(av*av);
    if (lane == 0){ red[(wid*C + c)*2] = s; red[(wid*C + c)*2 + 1] = q; }
  }
  __syncthreads();
  if ((int)threadIdx.x < C){
    double s = 0.0, q = 0.0;
    #pragma unroll
    for (int wv = 0; wv < 4; ++wv){ s += red[(wv*C + threadIdx.x)*2]; q += red[(wv*C + threadIdx.x)*2 + 1]; }
    atomicAdd(&gsum[2*threadIdx.x],     s);
    atomicAdd(&gsum[2*threadIdx.x + 1], q);
  }
}

// stats from 2 per-thread pixel arrays (combined f64 before shuffle tree)
template<int C>
__device__ __forceinline__ void ae9_statsf2(const float* a0, const float* a1, double* red, double* gsum){
  const int lane = threadIdx.x & 63, wid = threadIdx.x >> 6;
  #pragma unroll
  for (int c = 0; c < C; ++c){
    double v0 = (double)a0[c], v1 = (double)a1[c];
    double s = ae9_wsumd(v0 + v1);
    double q = ae9_wsumd(v0*v0 + v1*v1);
    if (lane == 0){ red[(wid*C + c)*2] = s; red[(wid*C + c)*2 + 1] = q; }
  }
  __syncthreads();
  if ((int)threadIdx.x < C){
    double s = 0.0, q = 0.0;
    #pragma unroll
    for (int wv = 0; wv < 4; ++wv){ s += red[(wv*C + threadIdx.x)*2]; q += red[(wv*C + threadIdx.x)*2 + 1]; }
    atomicAdd(&gsum[2*threadIdx.x],     s);
    atomicAdd(&gsum[2*threadIdx.x + 1], q);
  }
}

template<int C>
__device__ __forceinline__ void ae9_bnparams(float* pm, float* pr, float* pg, float* pb,
                                             const double* sums, const float* g, const float* be, double inv){
  if ((int)threadIdx.x < C){
    int c = threadIdx.x;
    double md = sums[2*c] * inv;
    double vd = sums[2*c+1] * inv - md*md;
    pm[c] = (float)md;
    float vf = (float)vd;
    pr[c] = __fdiv_rn(1.f, __fsqrt_rn(__fadd_rn(vf, 1e-5f)));
    pg[c] = g[c];
    pb[c] = be[c];
  }
  __syncthreads();
}

__device__ __forceinline__ float ae9_bn(float x, float m, float g, float r, float b){
  return __fadd_rn(__fmul_rn(__fmul_rn(g, __fsub_rn(x, m)), r), b);
}
__device__ __forceinline__ float ae9_bnrelu(float x, float m, float g, float r, float b){
  return fmaxf(ae9_bn(x, m, g, r, b), 0.f);
}

__device__ __forceinline__ float ae9_np_pairwise32(const float* a){
  float r[8];
  #pragma unroll
  for (int j = 0; j < 8; ++j)
    r[j] = __fadd_rn(__fadd_rn(__fadd_rn(a[j], a[8+j]), a[16+j]), a[24+j]);
  return __fadd_rn(__fadd_rn(__fadd_rn(r[0], r[1]), __fadd_rn(r[2], r[3])),
                   __fadd_rn(__fadd_rn(r[4], r[5]), __fadd_rn(r[6], r[7])));
}

// ---------- prep (zeroes sums + weight transposes + ||e||^2) ----------
__global__ void ae9_prep(const float* __restrict__ w1, const float* __restrict__ w2,
                         const float* __restrict__ w3, const float* __restrict__ dw1,
                         const float* __restrict__ dtw1, const float* __restrict__ dtw2,
                         const float* __restrict__ emb, char* __restrict__ wsb){
  const int t = threadIdx.x;
  double* sums = (double*)(wsb + WS_SUMS);
  sums[t] = 0.0;
  sums[t + 256] = 0.0;
  float* w1T  = (float*)(wsb + WS_W1T);
  float* w2T  = (float*)(wsb + WS_W2T);
  float* w3T  = (float*)(wsb + WS_W3T);
  float* dw1T = (float*)(wsb + WS_DW1T);
  float* dt1T = (float*)(wsb + WS_DT1T);
  float* dt2T = (float*)(wsb + WS_DT2T);
  float* e2f  = (float*)(wsb + WS_E2F);
  if (t < 256) w1T[t] = w1[(t & 15)*16 + (t >> 4)];
  for (int i = t; i < 8192; i += 256){
    int co = i & 31, k = i >> 5;
    w2T[i] = w2[co*256 + k];
  }
  for (int i = t; i < 1024; i += 256){ int co = i & 31, ci = i >> 5; w3T[i]  = w3[co*32 + ci]; }
  for (int i = t; i < 1024; i += 256){ int co = i & 31, ci = i >> 5; dw1T[i] = dw1[co*32 + ci]; }
  for (int i = t; i < 8192; i += 256){
    int co = i & 15, ci = (i >> 4) & 31, tap = i >> 9;
    dt1T[i] = dtw1[(ci*16 + co)*16 + tap];
  }
  for (int i = t; i < 8192; i += 256){
    int co = i & 31; int r2 = i >> 5; int ci = r2 & 15; int tap = r2 >> 4;
    dt2T[i] = (co < 30) ? dtw2[(ci*30 + co)*16 + tap] : 0.f;
  }
  for (int k = t; k < 512; k += 256){
    float sq[32];
    #pragma unroll
    for (int c = 0; c < 32; ++c){ float e = emb[k*32 + c]; sq[c] = __fmul_rn(e, e); }
    e2f[k] = ae9_np_pairwise32(sq);
  }
}

// ---------- conv1 v2: 2 px/thread (stats tree amortized); per-pixel math identical ----------
__global__ void __launch_bounds__(256) aeF_conv1(const float* __restrict__ x, const float* __restrict__ w1T,
                         const float* __restrict__ b1, float* __restrict__ y1, double* __restrict__ sums1){
  __shared__ double red[4*16*2];
  const int idx = blockIdx.x*256 + threadIdx.x;       // 262144 threads, 2 px each
  float yv0[16], yv1[16];
  #pragma unroll
  for (int i = 0; i < 2; ++i){
    const int pix = idx + i*262144;
    const int ox = pix & 127, oy = (pix >> 7) & 127, n = pix >> 14;
    float acc[16];
    #pragma unroll
    for (int c = 0; c < 16; ++c) acc[c] = 0.f;
    const float* xp = x + n*65536;
    for (int ky = 0; ky < 4; ++ky){
      int iy = 2*oy - 1 + ky;
      if (iy < 0 || iy >= 256) continue;
      for (int kx = 0; kx < 4; ++kx){
        int ix = 2*ox - 1 + kx;
        if (ix < 0 || ix >= 256) continue;
        float v = xp[iy*256 + ix];
        const float* w = w1T + (ky*4 + kx)*16;
        #pragma unroll
        for (int c = 0; c < 16; ++c) acc[c] = __fmaf_rn(v, w[c], acc[c]);
      }
    }
    float* yp = y1 + n*262144 + oy*128 + ox;
    float* yv = i ? yv1 : yv0;
    #pragma unroll
    for (int c = 0; c < 16; ++c){ yv[c] = __fadd_rn(acc[c], b1[c]); yp[c*16384] = yv[c]; }
  }
  ae9_statsf2<16>(yv0, yv1, red, sums1);
}

// ---------- conv2 (UNCHANGED encoder) ----------
__global__ void __launch_bounds__(256) ae9_conv2(const float* __restrict__ y1, const double* __restrict__ sums1,
                         const float* __restrict__ g1, const float* __restrict__ be1,
                         const float* __restrict__ w2T, const float* __restrict__ b2,
                         float* __restrict__ y2, double* __restrict__ sums2){
  __shared__ float pm[16], pr[16], pg[16], pb[16];
  __shared__ double red[4*32*2];
  ae9_bnparams<16>(pm, pr, pg, pb, sums1, g1, be1, 1.0/524288.0);
  const int idx = blockIdx.x*256 + threadIdx.x;
  const int ox = idx & 63, oy = (idx >> 6) & 63, n = idx >> 12;
  float acc[32];
  #pragma unroll
  for (int c = 0; c < 32; ++c) acc[c] = 0.f;
  const float* in = y1 + n*262144;
  for (int ci = 0; ci < 16; ++ci){
    const float m = pm[ci], g = pg[ci], r = pr[ci], b = pb[ci];
    const float* plane = in + ci*16384;
    for (int ky = 0; ky < 4; ++ky){
      int iy = 2*oy - 1 + ky;
      if (iy < 0 || iy >= 128) continue;
      for (int kx = 0; kx < 4; ++kx){
        int ix = 2*ox - 1 + kx;
        if (ix < 0 || ix >= 128) continue;
        float v = ae9_bnrelu(plane[iy*128 + ix], m, g, r, b);
        const float* w = w2T + (ci*16 + ky*4 + kx)*32;
        #pragma unroll
        for (int co = 0; co < 32; ++co) acc[co] = __fmaf_rn(v, w[co], acc[co]);
      }
    }
  }
  float yv[32];
  float* yp = y2 + n*131072 + oy*64 + ox;
  #pragma unroll
  for (int c = 0; c < 32; ++c){ yv[c] = __fadd_rn(acc[c], b2[c]); yp[c*4096] = yv[c]; }
  ae9_statsf<32>(yv, red, sums2);
}

// ---------- conv3 (UNCHANGED encoder) ----------
__global__ void __launch_bounds__(256) ae9_conv3(const float* __restrict__ y2, const double* __restrict__ sums2,
                         const float* __restrict__ g2, const float* __restrict__ be2,
                         const float* __restrict__ w3T, const float* __restrict__ b3,
                         float* __restrict__ y3, double* __restrict__ sums3){
  __shared__ float pm[32], pr[32], pg[32], pb[32];
  __shared__ double red[4*32*2];
  ae9_bnparams<32>(pm, pr, pg, pb, sums2, g2, be2, 1.0/131072.0);
  const int idx = blockIdx.x*256 + threadIdx.x;
  const int sp = idx & 4095, n = idx >> 12;
  const float* in = y2 + n*131072 + sp;
  float acc[32];
  #pragma unroll
  for (int c = 0; c < 32; ++c) acc[c] = 0.f;
  for (int ci = 0; ci < 32; ++ci){
    float v = ae9_bnrelu(in[ci*4096], pm[ci], pg[ci], pr[ci], pb[ci]);
    const float* w = w3T + ci*32;
    #pragma unroll
    for (int co = 0; co < 32; ++co) acc[co] = __fmaf_rn(v, w[co], acc[co]);
  }
  float yv[32];
  float* yp = y3 + n*131072 + sp;
  #pragma unroll
  for (int c = 0; c < 32; ++c){ yv[c] = __fadd_rn(acc[c], b3[c]); yp[c*4096] = yv[c]; }
  ae9_statsf<32>(yv, red, sums3);
}

// ---------- VQ v4 (unchanged): chunked LDS staging, full occupancy ----------
__global__ void __launch_bounds__(256) aeE_vq(const float* __restrict__ y3, const double* __restrict__ sums3,
                      const float* __restrict__ g3, const float* __restrict__ be3,
                      const float* __restrict__ emb, const float* __restrict__ e2f,
                      const float* __restrict__ dw1T, const float* __restrict__ db1,
                      float* __restrict__ y4, double* __restrict__ sums4,
                      float* __restrict__ out){
  __shared__ float pm[32], pr[32], pg[32], pb[32];
  __shared__ double red[4*32*2];
  __shared__ float embL[4096];                         // 128 codes x 32 = 16 KB
  ae9_bnparams<32>(pm, pr, pg, pb, sums3, g3, be3, 1.0/131072.0);
  const int idx = blockIdx.x*256 + threadIdx.x;        // 512 blocks x 256 px
  const int sp = idx & 4095, n = idx >> 12;
  const float* in = y3 + n*131072 + sp;
  float zf[32], z2q[32], zf2[32];
  #pragma unroll
  for (int c = 0; c < 32; ++c){
    zf[c]  = ae9_bn(in[c*4096], pm[c], pg[c], pr[c], pb[c]);
    z2q[c] = __fmul_rn(zf[c], zf[c]);
    zf2[c] = __fmul_rn(2.0f, zf[c]);
  }
  float* ze = out + OUT_ZE + n*131072 + sp;
  #pragma unroll
  for (int c = 0; c < 32; ++c) ze[c*4096] = zf[c];
  const float z2 = ae9_np_pairwise32(z2q);
  float best = 3.4e38f; int bi = 0;
  for (int c0 = 0; c0 < 512; c0 += 128){               // 4 ascending chunks
    __syncthreads();
    {
      const float4* src = reinterpret_cast<const float4*>(emb + c0*32);
      float4* dst = reinterpret_cast<float4*>(embL);
      for (int i = threadIdx.x; i < 1024; i += 256) dst[i] = src[i];
    }
    __syncthreads();
    for (int k = c0; k < c0 + 128; k += 8){
      float d8[8];
      #pragma unroll
      for (int j = 0; j < 8; ++j){
        const float* ek = embL + (k - c0 + j)*32;
        float acc = 0.f;
        #pragma unroll
        for (int c = 0; c < 32; ++c) acc = __fmaf_rn(zf2[c], ek[c], acc);
        float u = __fsub_rn(z2, acc);
        d8[j] = __fadd_rn(u, e2f[k + j]);
      }
      #pragma unroll
      for (int j = 0; j < 8; ++j)
        if (d8[j] < best){ best = d8[j]; bi = k + j; }
    }
  }
  out[OUT_LT + idx] = (float)bi;
  const float4* er = reinterpret_cast<const float4*>(emb + bi*32);
  float* zq = out + OUT_ZQ + n*131072 + sp;
  float acc[32];
  #pragma unroll
  for (int c = 0; c < 32; ++c) acc[c] = db1[c];
  #pragma unroll
  for (int j = 0; j < 8; ++j){
    float4 f = er[j];
    zq[(4*j+0)*4096] = f.x;
    zq[(4*j+1)*4096] = f.y;
    zq[(4*j+2)*4096] = f.z;
    zq[(4*j+3)*4096] = f.w;
    const float* w0 = dw1T + (4*j + 0)*32;
    const float* w1 = dw1T + (4*j + 1)*32;
    const float* w2 = dw1T + (4*j + 2)*32;
    const float* w3 = dw1T + (4*j + 3)*32;
    #pragma unroll
    for (int co = 0; co < 32; ++co){
      acc[co] = fmaf(f.x, w0[co], acc[co]);
      acc[co] = fmaf(f.y, w1[co], acc[co]);
      acc[co] = fmaf(f.z, w2[co], acc[co]);
      acc[co] = fmaf(f.w, w3[co], acc[co]);
    }
  }
  float* yp = y4 + n*131072 + sp;
  #pragma unroll
  for (int c = 0; c < 32; ++c) yp[c*4096] = acc[c];
  ae9_statsf<32>(acc, red, sums4);
}

// ---------- dect1 v4: wave = (n, oy-pair, parity); 2 rows/wave (oy, oy+64) ----------
__global__ void __launch_bounds__(256) aeF_dect1(const float* __restrict__ y4, const double* __restrict__ sums4,
                         const float* __restrict__ g4, const float* __restrict__ be4,
                         const float* __restrict__ wT, const float* __restrict__ bias,
                         float* __restrict__ y5, double* __restrict__ sums5){
  __shared__ float pm[32], pr[32], pg[32], pb[32];
  __shared__ double red[4*16*2];
  ae9_bnparams<32>(pm, pr, pg, pb, sums4, g4, be4, 1.0/131072.0);
  const int w = __builtin_amdgcn_readfirstlane(blockIdx.x*4 + (threadIdx.x >> 6)); // 4096 waves
  const int j = threadIdx.x & 63;
  const int p = w & 1, oy = (w >> 1) & 63, n = w >> 7;   // rows oy and oy+64 (same parity)
  const int ky0 = (oy & 1) ? 0 : 1;
  float a0[16], a1[16];
  #pragma unroll
  for (int c = 0; c < 16; ++c){ a0[c] = bias[c]; a1[c] = bias[c]; }
  const float* in = y4 + n*131072;
  for (int ci = 0; ci < 32; ++ci){
    const float m = pm[ci], g = pg[ci], r = pr[ci], b = pb[ci];
    const float* plane = in + ci*4096;
    #pragma unroll
    for (int ty = 0; ty < 2; ++ty){
      const int ky = ky0 + 2*ty;
      const int iyA = (oy + 1 - ky) >> 1;                // row A
      const int iyB = iyA + 32;                          // row B = oy+64
      #pragma unroll
      for (int tx = 0; tx < 2; ++tx){
        const int kx = p ? 2*tx : 1 + 2*tx;              // wave-uniform
        const float4* wv = reinterpret_cast<const float4*>(wT + ((ky*4 + kx)*32 + ci)*16);
        float wgt[16];
        #pragma unroll
        for (int q = 0; q < 4; ++q) reinterpret_cast<float4*>(wgt)[q] = wv[q];
        const int ix = j + p - tx;
        const bool vx = (ix >= 0 && ix < 64);
        float vA = (vx && iyA >= 0)      ? ae9_bnrelu(plane[iyA*64 + ix], m, g, r, b) : 0.f;  // iyA<64 always (oy<=63)
        float vB = (vx && iyB < 64)      ? ae9_bnrelu(plane[iyB*64 + ix], m, g, r, b) : 0.f;  // iyB>=32>=0 always
        #pragma unroll
        for (int co = 0; co < 16; ++co){
          a0[co] = fmaf(vA, wgt[co], a0[co]);
          a1[co] = fmaf(vB, wgt[co], a1[co]);
        }
      }
    }
  }
  float* opA = y5 + ((size_t)n*16)*16384 + oy*128 + p;
  float* opB = opA + 64*128;
  #pragma unroll
  for (int co = 0; co < 16; ++co){
    opA[co*16384 + 2*j] = a0[co];
    opB[co*16384 + 2*j] = a1[co];
  }
  ae9_statsf2<16>(a0, a1, red, sums5);
}

// ---------- dect2 v4: float4 weight chunks (VGPR cut -> higher occupancy); acc[32] pads dead ----------
__global__ void __launch_bounds__(256) aeF_dect2(const float* __restrict__ y5, const double* __restrict__ sums5,
                         const float* __restrict__ g5, const float* __restrict__ be5,
                         const float* __restrict__ wT, const float* __restrict__ bias,
                         float* __restrict__ out){
  __shared__ float pm[16], pr[16], pg[16], pb[16];
  ae9_bnparams<16>(pm, pr, pg, pb, sums5, g5, be5, 1.0/524288.0);
  const int w = __builtin_amdgcn_readfirstlane(blockIdx.x*4 + (threadIdx.x >> 6)); // 16384 waves
  const int j = threadIdx.x & 63;
  const int p = w & 1, oy = (w >> 1) & 255, n = w >> 9;
  const int ky0 = (oy & 1) ? 0 : 1;
  float a0[32], a1[32];                                  // slots 30,31 are dead (padded weights = 0)
  #pragma unroll
  for (int c = 0; c < 30; ++c){ a0[c] = bias[c]; a1[c] = bias[c]; }
  a0[30] = a0[31] = a1[30] = a1[31] = 0.f;
  const float* in = y5 + n*262144;
  for (int ci = 0; ci < 16; ++ci){
    const float m = pm[ci], g = pg[ci], r = pr[ci], b = pb[ci];
    const float* plane = in + ci*16384;
    #pragma unroll
    for (int ty = 0; ty < 2; ++ty){
      const int ky = ky0 + 2*ty;
      const int iy = (oy + 1 - ky) >> 1;
      if (iy < 0 || iy >= 128) continue;                 // wave-uniform
      const float* row = plane + iy*128;
      #pragma unroll
      for (int tx = 0; tx < 2; ++tx){
        const int kx = p ? 2*tx : 1 + 2*tx;              // wave-uniform
        const float4* wv = reinterpret_cast<const float4*>(wT + ((ky*4 + kx)*16 + ci)*32);
        int ix0 = j + p - tx;
        int ix1 = ix0 + 64;
        float v0 = (ix0 >= 0 && ix0 < 128) ? ae9_bnrelu(row[ix0], m, g, r, b) : 0.f;
        float v1 = (ix1 >= 0 && ix1 < 128) ? ae9_bnrelu(row[ix1], m, g, r, b) : 0.f;
        #pragma unroll
        for (int q = 0; q < 8; ++q){
          float4 wq = wv[q];
          const float we[4] = {wq.x, wq.y, wq.z, wq.w};
          #pragma unroll
          for (int e = 0; e < 4; ++e){
            const int co = 4*q + e;
            a0[co] = fmaf(v0, we[e], a0[co]);
            a1[co] = fmaf(v1, we[e], a1[co]);
          }
        }
      }
    }
  }
  float* op = out + OUT_XT + ((size_t)n*30)*65536 + oy*256 + p;
  #pragma unroll
  for (int co = 0; co < 30; ++co){
    op[co*65536 + 2*j]        = a0[co];
    op[co*65536 + 2*(j + 64)] = a1[co];
  }
}

extern "C" void kernel_launch(void* const* d_in, const int* in_sizes, int n_in,
                              void* d_out, int out_size, void* d_ws, size_t ws_size,
                              hipStream_t stream) {
  const float* x    = (const float*)d_in[0];
  const float* w1   = (const float*)d_in[1];
  const float* b1   = (const float*)d_in[2];
  const float* g1   = (const float*)d_in[3];
  const float* be1  = (const float*)d_in[4];
  const float* w2   = (const float*)d_in[5];
  const float* b2   = (const float*)d_in[6];
  const float* g2   = (const float*)d_in[7];
  const float* be2  = (const float*)d_in[8];
  const float* w3   = (const float*)d_in[9];
  const float* b3   = (const float*)d_in[10];
  const float* g3   = (const float*)d_in[11];
  const float* be3  = (const float*)d_in[12];
  const float* emb  = (const float*)d_in[13];
  const float* dw1  = (const float*)d_in[14];
  const float* db1  = (const float*)d_in[15];
  const float* dg1  = (const float*)d_in[16];
  const float* dbe1 = (const float*)d_in[17];
  const float* dtw1 = (const float*)d_in[18];
  const float* dtb1 = (const float*)d_in[19];
  const float* dg2  = (const float*)d_in[20];
  const float* dbe2 = (const float*)d_in[21];
  const float* dtw2 = (const float*)d_in[22];
  const float* dtb2 = (const float*)d_in[23];

  char* wsb = (char*)d_ws;
  char* ob  = (char*)d_out;
  float* out = (float*)d_out;

  double* sums1 = (double*)(wsb + WS_SUMS + SUM1);
  double* sums2 = (double*)(wsb + WS_SUMS + SUM2);
  double* sums3 = (double*)(wsb + WS_SUMS + SUM3);
  double* sums4 = (double*)(wsb + WS_SUMS + SUM4);
  double* sums5 = (double*)(wsb + WS_SUMS + SUM5);
  float* y1 = (float*)(wsb + WS_Y1);
  float* y5 = (float*)(wsb + WS_Y5);
  float* y2 = (float*)(ob + DO_Y2);
  float* y3 = (float*)(ob + DO_Y3);
  float* y4 = (float*)(ob + DO_Y4);

  ae9_prep<<<1, 256, 0, stream>>>(w1, w2, w3, dw1, dtw1, dtw2, emb, wsb);
  aeF_conv1<<<1024, 256, 0, stream>>>(x, (const float*)(wsb + WS_W1T), b1, y1, sums1);
  ae9_conv2<<<512, 256, 0, stream>>>(y1, sums1, g1, be1, (const float*)(wsb + WS_W2T), b2, y2, sums2);
  ae9_conv3<<<512, 256, 0, stream>>>(y2, sums2, g2, be2, (const float*)(wsb + WS_W3T), b3, y3, sums3);
  aeE_vq<<<512, 256, 0, stream>>>(y3, sums3, g3, be3, emb, (const float*)(wsb + WS_E2F),
                                  (const float*)(wsb + WS_DW1T), db1, y4, sums4, out);
  aeF_dect1<<<1024, 256, 0, stream>>>(y4, sums4, dg1, dbe1, (const float*)(wsb + WS_DT1T), dtb1, y5, sums5);
  aeF_dect2<<<4096, 256, 0, stream>>>(y5, sums5, dg2, dbe2, (const float*)(wsb + WS_DT2T), dtb2, out);
}

// Round 20
// 592.294 us; speedup vs baseline: 1.0892x; 1.0046x over previous
//
#include <hip/hip_runtime.h>
#include <hip/hip_bf16.h>

// ======== d_ws byte offsets ========
#define WS_SUMS  0          // 5 zones x {sum,sumsq} f64 (512 doubles); zeroed by ae9_prep each launch
#define WS_W1T   4096       // 256 f32
#define WS_W2T   8192       // 8192 f32 -> 40960
#define WS_W3T   40960      // 1024 f32
#define WS_DW1T  45056      // 1024 f32
#define WS_DT1T  49152      // 8192 f32 -> 81920
#define WS_DT2T  81920      // 8192 f32 (padded co-stride 32) -> 114688
#define WS_E2F   114688     // 512 f32 -> 116736
#define WS_Y1    1048576    // f32 (32,16,128,128) 33,554,432 B ; dead after conv2
#define WS_Y5    1048576    // f32 (32,16,128,128) reuses Y1 slot ; dead after dect2

#define SUM1 0
#define SUM2 512
#define SUM3 1024
#define SUM4 1536
#define SUM5 2048

// ======== d_out FLOAT32 element offsets ========
#define OUT_XT 0
#define OUT_ZE 62914560
#define OUT_ZQ 67108864
#define OUT_LT 71303168

// ======== scratch inside d_out's x_tilde byte range ========
#define DO_Y2 0            // f32 (32,32,64,64) ; dead after conv3
#define DO_Y3 16777216     // f32 (32,32,64,64) ; dead after vq
#define DO_Y4 33554432     // f32 (32,32,64,64) ; dead after dect1

__device__ __forceinline__ double ae9_wsumd(double v){
  #pragma unroll
  for (int off = 32; off; off >>= 1) v += __shfl_xor(v, off);
  return v;
}

template<int C>
__device__ __forceinline__ void ae9_statsf(const float* a, double* red, double* gsum){
  const int lane = threadIdx.x & 63, wid = threadIdx.x >> 6;
  #pragma unroll
  for (int c = 0; c < C; ++c){
    double av = (double)a[c];
    double s = ae9_wsumd(av);
    double q = ae9_wsumd(av*av);
    if (lane == 0){ red[(wid*C + c)*2] = s; red[(wid*C + c)*2 + 1] = q; }
  }
  __syncthreads();
  if ((int)threadIdx.x < C){
    double s = 0.0, q = 0.0;
    #pragma unroll
    for (int wv = 0; wv < 4; ++wv){ s += red[(wv*C + threadIdx.x)*2]; q += red[(wv*C + threadIdx.x)*2 + 1]; }
    atomicAdd(&gsum[2*threadIdx.x],     s);
    atomicAdd(&gsum[2*threadIdx.x + 1], q);
  }
}

// stats from 2 per-thread pixel arrays (combined f64 before shuffle tree)
template<int C>
__device__ __forceinline__ void ae9_statsf2(const float* a0, const float* a1, double* red, double* gsum){
  const int lane = threadIdx.x & 63, wid = threadIdx.x >> 6;
  #pragma unroll
  for (int c = 0; c < C; ++c){
    double v0 = (double)a0[c], v1 = (double)a1[c];
    double s = ae9_wsumd(v0 + v1);
    double q = ae9_wsumd(v0*v0 + v1*v1);
    if (lane == 0){ red[(wid*C + c)*2] = s; red[(wid*C + c)*2 + 1] = q; }
  }
  __syncthreads();
  if ((int)threadIdx.x < C){
    double s = 0.0, q = 0.0;
    #pragma unroll
    for (int wv = 0; wv < 4; ++wv){ s += red[(wv*C + threadIdx.x)*2]; q += red[(wv*C + threadIdx.x)*2 + 1]; }
    atomicAdd(&gsum[2*threadIdx.x],     s);
    atomicAdd(&gsum[2*threadIdx.x + 1], q);
  }
}

template<int C>
__device__ __forceinline__ void ae9_bnparams(float* pm, float* pr, float* pg, float* pb,
                                             const double* sums, const float* g, const float* be, double inv){
  if ((int)threadIdx.x < C){
    int c = threadIdx.x;
    double md = sums[2*c] * inv;
    double vd = sums[2*c+1] * inv - md*md;
    pm[c] = (float)md;
    float vf = (float)vd;
    pr[c] = __fdiv_rn(1.f, __fsqrt_rn(__fadd_rn(vf, 1e-5f)));
    pg[c] = g[c];
    pb[c] = be[c];
  }
  __syncthreads();
}

__device__ __forceinline__ float ae9_bn(float x, float m, float g, float r, float b){
  return __fadd_rn(__fmul_rn(__fmul_rn(g, __fsub_rn(x, m)), r), b);
}
__device__ __forceinline__ float ae9_bnrelu(float x, float m, float g, float r, float b){
  return fmaxf(ae9_bn(x, m, g, r, b), 0.f);
}

__device__ __forceinline__ float ae9_np_pairwise32(const float* a){
  float r[8];
  #pragma unroll
  for (int j = 0; j < 8; ++j)
    r[j] = __fadd_rn(__fadd_rn(__fadd_rn(a[j], a[8+j]), a[16+j]), a[24+j]);
  return __fadd_rn(__fadd_rn(__fadd_rn(r[0], r[1]), __fadd_rn(r[2], r[3])),
                   __fadd_rn(__fadd_rn(r[4], r[5]), __fadd_rn(r[6], r[7])));
}

// ---------- prep (zeroes sums + weight transposes + ||e||^2) ----------
__global__ void ae9_prep(const float* __restrict__ w1, const float* __restrict__ w2,
                         const float* __restrict__ w3, const float* __restrict__ dw1,
                         const float* __restrict__ dtw1, const float* __restrict__ dtw2,
                         const float* __restrict__ emb, char* __restrict__ wsb){
  const int t = threadIdx.x;
  double* sums = (double*)(wsb + WS_SUMS);
  sums[t] = 0.0;
  sums[t + 256] = 0.0;
  float* w1T  = (float*)(wsb + WS_W1T);
  float* w2T  = (float*)(wsb + WS_W2T);
  float* w3T  = (float*)(wsb + WS_W3T);
  float* dw1T = (float*)(wsb + WS_DW1T);
  float* dt1T = (float*)(wsb + WS_DT1T);
  float* dt2T = (float*)(wsb + WS_DT2T);
  float* e2f  = (float*)(wsb + WS_E2F);
  if (t < 256) w1T[t] = w1[(t & 15)*16 + (t >> 4)];
  for (int i = t; i < 8192; i += 256){
    int co = i & 31, k = i >> 5;
    w2T[i] = w2[co*256 + k];
  }
  for (int i = t; i < 1024; i += 256){ int co = i & 31, ci = i >> 5; w3T[i]  = w3[co*32 + ci]; }
  for (int i = t; i < 1024; i += 256){ int co = i & 31, ci = i >> 5; dw1T[i] = dw1[co*32 + ci]; }
  for (int i = t; i < 8192; i += 256){
    int co = i & 15, ci = (i >> 4) & 31, tap = i >> 9;
    dt1T[i] = dtw1[(ci*16 + co)*16 + tap];
  }
  for (int i = t; i < 8192; i += 256){
    int co = i & 31; int r2 = i >> 5; int ci = r2 & 15; int tap = r2 >> 4;
    dt2T[i] = (co < 30) ? dtw2[(ci*30 + co)*16 + tap] : 0.f;
  }
  for (int k = t; k < 512; k += 256){
    float sq[32];
    #pragma unroll
    for (int c = 0; c < 32; ++c){ float e = emb[k*32 + c]; sq[c] = __fmul_rn(e, e); }
    e2f[k] = ae9_np_pairwise32(sq);
  }
}

// ---------- conv1 v2: 2 px/thread (stats tree amortized) ----------
__global__ void __launch_bounds__(256) aeF_conv1(const float* __restrict__ x, const float* __restrict__ w1T,
                         const float* __restrict__ b1, float* __restrict__ y1, double* __restrict__ sums1){
  __shared__ double red[4*16*2];
  const int idx = blockIdx.x*256 + threadIdx.x;       // 262144 threads, 2 px each
  float yv0[16], yv1[16];
  #pragma unroll
  for (int i = 0; i < 2; ++i){
    const int pix = idx + i*262144;
    const int ox = pix & 127, oy = (pix >> 7) & 127, n = pix >> 14;
    float acc[16];
    #pragma unroll
    for (int c = 0; c < 16; ++c) acc[c] = 0.f;
    const float* xp = x + n*65536;
    for (int ky = 0; ky < 4; ++ky){
      int iy = 2*oy - 1 + ky;
      if (iy < 0 || iy >= 256) continue;
      for (int kx = 0; kx < 4; ++kx){
        int ix = 2*ox - 1 + kx;
        if (ix < 0 || ix >= 256) continue;
        float v = xp[iy*256 + ix];
        const float* w = w1T + (ky*4 + kx)*16;
        #pragma unroll
        for (int c = 0; c < 16; ++c) acc[c] = __fmaf_rn(v, w[c], acc[c]);
      }
    }
    float* yp = y1 + n*262144 + oy*128 + ox;
    float* yv = i ? yv1 : yv0;
    #pragma unroll
    for (int c = 0; c < 16; ++c){ yv[c] = __fadd_rn(acc[c], b1[c]); yp[c*16384] = yv[c]; }
  }
  ae9_statsf2<16>(yv0, yv1, red, sums1);
}

// ---------- conv2 (UNCHANGED encoder) ----------
__global__ void __launch_bounds__(256) ae9_conv2(const float* __restrict__ y1, const double* __restrict__ sums1,
                         const float* __restrict__ g1, const float* __restrict__ be1,
                         const float* __restrict__ w2T, const float* __restrict__ b2,
                         float* __restrict__ y2, double* __restrict__ sums2){
  __shared__ float pm[16], pr[16], pg[16], pb[16];
  __shared__ double red[4*32*2];
  ae9_bnparams<16>(pm, pr, pg, pb, sums1, g1, be1, 1.0/524288.0);
  const int idx = blockIdx.x*256 + threadIdx.x;
  const int ox = idx & 63, oy = (idx >> 6) & 63, n = idx >> 12;
  float acc[32];
  #pragma unroll
  for (int c = 0; c < 32; ++c) acc[c] = 0.f;
  const float* in = y1 + n*262144;
  for (int ci = 0; ci < 16; ++ci){
    const float m = pm[ci], g = pg[ci], r = pr[ci], b = pb[ci];
    const float* plane = in + ci*16384;
    for (int ky = 0; ky < 4; ++ky){
      int iy = 2*oy - 1 + ky;
      if (iy < 0 || iy >= 128) continue;
      for (int kx = 0; kx < 4; ++kx){
        int ix = 2*ox - 1 + kx;
        if (ix < 0 || ix >= 128) continue;
        float v = ae9_bnrelu(plane[iy*128 + ix], m, g, r, b);
        const float* w = w2T + (ci*16 + ky*4 + kx)*32;
        #pragma unroll
        for (int co = 0; co < 32; ++co) acc[co] = __fmaf_rn(v, w[co], acc[co]);
      }
    }
  }
  float yv[32];
  float* yp = y2 + n*131072 + oy*64 + ox;
  #pragma unroll
  for (int c = 0; c < 32; ++c){ yv[c] = __fadd_rn(acc[c], b2[c]); yp[c*4096] = yv[c]; }
  ae9_statsf<32>(yv, red, sums2);
}

// ---------- conv3 (UNCHANGED encoder) ----------
__global__ void __launch_bounds__(256) ae9_conv3(const float* __restrict__ y2, const double* __restrict__ sums2,
                         const float* __restrict__ g2, const float* __restrict__ be2,
                         const float* __restrict__ w3T, const float* __restrict__ b3,
                         float* __restrict__ y3, double* __restrict__ sums3){
  __shared__ float pm[32], pr[32], pg[32], pb[32];
  __shared__ double red[4*32*2];
  ae9_bnparams<32>(pm, pr, pg, pb, sums2, g2, be2, 1.0/131072.0);
  const int idx = blockIdx.x*256 + threadIdx.x;
  const int sp = idx & 4095, n = idx >> 12;
  const float* in = y2 + n*131072 + sp;
  float acc[32];
  #pragma unroll
  for (int c = 0; c < 32; ++c) acc[c] = 0.f;
  for (int ci = 0; ci < 32; ++ci){
    float v = ae9_bnrelu(in[ci*4096], pm[ci], pg[ci], pr[ci], pb[ci]);
    const float* w = w3T + ci*32;
    #pragma unroll
    for (int co = 0; co < 32; ++co) acc[co] = __fmaf_rn(v, w[co], acc[co]);
  }
  float yv[32];
  float* yp = y3 + n*131072 + sp;
  #pragma unroll
  for (int c = 0; c < 32; ++c){ yv[c] = __fadd_rn(acc[c], b3[c]); yp[c*4096] = yv[c]; }
  ae9_statsf<32>(yv, red, sums3);
}

// ---------- VQ v5: chunked LDS staging + float4 ds_read in the dot (same FMA order) ----------
__global__ void __launch_bounds__(256) aeG_vq(const float* __restrict__ y3, const double* __restrict__ sums3,
                      const float* __restrict__ g3, const float* __restrict__ be3,
                      const float* __restrict__ emb, const float* __restrict__ e2f,
                      const float* __restrict__ dw1T, const float* __restrict__ db1,
                      float* __restrict__ y4, double* __restrict__ sums4,
                      float* __restrict__ out){
  __shared__ float pm[32], pr[32], pg[32], pb[32];
  __shared__ double red[4*32*2];
  __shared__ float embL[4096];                         // 128 codes x 32 = 16 KB
  ae9_bnparams<32>(pm, pr, pg, pb, sums3, g3, be3, 1.0/131072.0);
  const int idx = blockIdx.x*256 + threadIdx.x;        // 512 blocks x 256 px
  const int sp = idx & 4095, n = idx >> 12;
  const float* in = y3 + n*131072 + sp;
  float zf[32], z2q[32], zf2[32];
  #pragma unroll
  for (int c = 0; c < 32; ++c){
    zf[c]  = ae9_bn(in[c*4096], pm[c], pg[c], pr[c], pb[c]);
    z2q[c] = __fmul_rn(zf[c], zf[c]);
    zf2[c] = __fmul_rn(2.0f, zf[c]);
  }
  float* ze = out + OUT_ZE + n*131072 + sp;
  #pragma unroll
  for (int c = 0; c < 32; ++c) ze[c*4096] = zf[c];
  const float z2 = ae9_np_pairwise32(z2q);
  float best = 3.4e38f; int bi = 0;
  for (int c0 = 0; c0 < 512; c0 += 128){               // 4 ascending chunks
    __syncthreads();
    {
      const float4* src = reinterpret_cast<const float4*>(emb + c0*32);
      float4* dst = reinterpret_cast<float4*>(embL);
      for (int i = threadIdx.x; i < 1024; i += 256) dst[i] = src[i];
    }
    __syncthreads();
    for (int k = c0; k < c0 + 128; k += 8){
      float d8[8];
      #pragma unroll
      for (int j = 0; j < 8; ++j){
        const float4* ek4 = reinterpret_cast<const float4*>(embL + (k - c0 + j)*32);
        float acc = 0.f;
        #pragma unroll
        for (int q = 0; q < 8; ++q){                   // ds_read_b128, same c=0..31 FMA order
          float4 e4 = ek4[q];
          acc = __fmaf_rn(zf2[4*q+0], e4.x, acc);
          acc = __fmaf_rn(zf2[4*q+1], e4.y, acc);
          acc = __fmaf_rn(zf2[4*q+2], e4.z, acc);
          acc = __fmaf_rn(zf2[4*q+3], e4.w, acc);
        }
        float u = __fsub_rn(z2, acc);
        d8[j] = __fadd_rn(u, e2f[k + j]);
      }
      #pragma unroll
      for (int j = 0; j < 8; ++j)
        if (d8[j] < best){ best = d8[j]; bi = k + j; } // strict <, first-min
    }
  }
  out[OUT_LT + idx] = (float)bi;
  const float4* er = reinterpret_cast<const float4*>(emb + bi*32);
  float* zq = out + OUT_ZQ + n*131072 + sp;
  float acc[32];
  #pragma unroll
  for (int c = 0; c < 32; ++c) acc[c] = db1[c];
  #pragma unroll
  for (int j = 0; j < 8; ++j){
    float4 f = er[j];
    zq[(4*j+0)*4096] = f.x;
    zq[(4*j+1)*4096] = f.y;
    zq[(4*j+2)*4096] = f.z;
    zq[(4*j+3)*4096] = f.w;
    const float* w0 = dw1T + (4*j + 0)*32;
    const float* w1 = dw1T + (4*j + 1)*32;
    const float* w2 = dw1T + (4*j + 2)*32;
    const float* w3 = dw1T + (4*j + 3)*32;
    #pragma unroll
    for (int co = 0; co < 32; ++co){
      acc[co] = fmaf(f.x, w0[co], acc[co]);
      acc[co] = fmaf(f.y, w1[co], acc[co]);
      acc[co] = fmaf(f.z, w2[co], acc[co]);
      acc[co] = fmaf(f.w, w3[co], acc[co]);
    }
  }
  float* yp = y4 + n*131072 + sp;
  #pragma unroll
  for (int c = 0; c < 32; ++c) yp[c*4096] = acc[c];
  ae9_statsf<32>(acc, red, sums4);
}

// ---------- dect1 v4 (unchanged): 2 rows/wave ----------
__global__ void __launch_bounds__(256) aeF_dect1(const float* __restrict__ y4, const double* __restrict__ sums4,
                         const float* __restrict__ g4, const float* __restrict__ be4,
                         const float* __restrict__ wT, const float* __restrict__ bias,
                         float* __restrict__ y5, double* __restrict__ sums5){
  __shared__ float pm[32], pr[32], pg[32], pb[32];
  __shared__ double red[4*16*2];
  ae9_bnparams<32>(pm, pr, pg, pb, sums4, g4, be4, 1.0/131072.0);
  const int w = __builtin_amdgcn_readfirstlane(blockIdx.x*4 + (threadIdx.x >> 6)); // 4096 waves
  const int j = threadIdx.x & 63;
  const int p = w & 1, oy = (w >> 1) & 63, n = w >> 7;   // rows oy and oy+64 (same parity)
  const int ky0 = (oy & 1) ? 0 : 1;
  float a0[16], a1[16];
  #pragma unroll
  for (int c = 0; c < 16; ++c){ a0[c] = bias[c]; a1[c] = bias[c]; }
  const float* in = y4 + n*131072;
  for (int ci = 0; ci < 32; ++ci){
    const float m = pm[ci], g = pg[ci], r = pr[ci], b = pb[ci];
    const float* plane = in + ci*4096;
    #pragma unroll
    for (int ty = 0; ty < 2; ++ty){
      const int ky = ky0 + 2*ty;
      const int iyA = (oy + 1 - ky) >> 1;
      const int iyB = iyA + 32;
      #pragma unroll
      for (int tx = 0; tx < 2; ++tx){
        const int kx = p ? 2*tx : 1 + 2*tx;
        const float4* wv = reinterpret_cast<const float4*>(wT + ((ky*4 + kx)*32 + ci)*16);
        float wgt[16];
        #pragma unroll
        for (int q = 0; q < 4; ++q) reinterpret_cast<float4*>(wgt)[q] = wv[q];
        const int ix = j + p - tx;
        const bool vx = (ix >= 0 && ix < 64);
        float vA = (vx && iyA >= 0) ? ae9_bnrelu(plane[iyA*64 + ix], m, g, r, b) : 0.f;
        float vB = (vx && iyB < 64) ? ae9_bnrelu(plane[iyB*64 + ix], m, g, r, b) : 0.f;
        #pragma unroll
        for (int co = 0; co < 16; ++co){
          a0[co] = fmaf(vA, wgt[co], a0[co]);
          a1[co] = fmaf(vB, wgt[co], a1[co]);
        }
      }
    }
  }
  float* opA = y5 + ((size_t)n*16)*16384 + oy*128 + p;
  float* opB = opA + 64*128;
  #pragma unroll
  for (int co = 0; co < 16; ++co){
    opA[co*16384 + 2*j] = a0[co];
    opB[co*16384 + 2*j] = a1[co];
  }
  ae9_statsf2<16>(a0, a1, red, sums5);
}

// ---------- dect2 v4 (unchanged): float4 weight chunks ----------
__global__ void __launch_bounds__(256) aeF_dect2(const float* __restrict__ y5, const double* __restrict__ sums5,
                         const float* __restrict__ g5, const float* __restrict__ be5,
                         const float* __restrict__ wT, const float* __restrict__ bias,
                         float* __restrict__ out){
  __shared__ float pm[16], pr[16], pg[16], pb[16];
  ae9_bnparams<16>(pm, pr, pg, pb, sums5, g5, be5, 1.0/524288.0);
  const int w = __builtin_amdgcn_readfirstlane(blockIdx.x*4 + (threadIdx.x >> 6)); // 16384 waves
  const int j = threadIdx.x & 63;
  const int p = w & 1, oy = (w >> 1) & 255, n = w >> 9;
  const int ky0 = (oy & 1) ? 0 : 1;
  float a0[32], a1[32];
  #pragma unroll
  for (int c = 0; c < 30; ++c){ a0[c] = bias[c]; a1[c] = bias[c]; }
  a0[30] = a0[31] = a1[30] = a1[31] = 0.f;
  const float* in = y5 + n*262144;
  for (int ci = 0; ci < 16; ++ci){
    const float m = pm[ci], g = pg[ci], r = pr[ci], b = pb[ci];
    const float* plane = in + ci*16384;
    #pragma unroll
    for (int ty = 0; ty < 2; ++ty){
      const int ky = ky0 + 2*ty;
      const int iy = (oy + 1 - ky) >> 1;
      if (iy < 0 || iy >= 128) continue;
      const float* row = plane + iy*128;
      #pragma unroll
      for (int tx = 0; tx < 2; ++tx){
        const int kx = p ? 2*tx : 1 + 2*tx;
        const float4* wv = reinterpret_cast<const float4*>(wT + ((ky*4 + kx)*16 + ci)*32);
        int ix0 = j + p - tx;
        int ix1 = ix0 + 64;
        float v0 = (ix0 >= 0 && ix0 < 128) ? ae9_bnrelu(row[ix0], m, g, r, b) : 0.f;
        float v1 = (ix1 >= 0 && ix1 < 128) ? ae9_bnrelu(row[ix1], m, g, r, b) : 0.f;
        #pragma unroll
        for (int q = 0; q < 8; ++q){
          float4 wq = wv[q];
          const float we[4] = {wq.x, wq.y, wq.z, wq.w};
          #pragma unroll
          for (int e = 0; e < 4; ++e){
            const int co = 4*q + e;
            a0[co] = fmaf(v0, we[e], a0[co]);
            a1[co] = fmaf(v1, we[e], a1[co]);
          }
        }
      }
    }
  }
  float* op = out + OUT_XT + ((size_t)n*30)*65536 + oy*256 + p;
  #pragma unroll
  for (int co = 0; co < 30; ++co){
    op[co*65536 + 2*j]        = a0[co];
    op[co*65536 + 2*(j + 64)] = a1[co];
  }
}

extern "C" void kernel_launch(void* const* d_in, const int* in_sizes, int n_in,
                              void* d_out, int out_size, void* d_ws, size_t ws_size,
                              hipStream_t stream) {
  const float* x    = (const float*)d_in[0];
  const float* w1   = (const float*)d_in[1];
  const float* b1   = (const float*)d_in[2];
  const float* g1   = (const float*)d_in[3];
  const float* be1  = (const float*)d_in[4];
  const float* w2   = (const float*)d_in[5];
  const float* b2   = (const float*)d_in[6];
  const float* g2   = (const float*)d_in[7];
  const float* be2  = (const float*)d_in[8];
  const float* w3   = (const float*)d_in[9];
  const float* b3   = (const float*)d_in[10];
  const float* g3   = (const float*)d_in[11];
  const float* be3  = (const float*)d_in[12];
  const float* emb  = (const float*)d_in[13];
  const float* dw1  = (const float*)d_in[14];
  const float* db1  = (const float*)d_in[15];
  const float* dg1  = (const float*)d_in[16];
  const float* dbe1 = (const float*)d_in[17];
  const float* dtw1 = (const float*)d_in[18];
  const float* dtb1 = (const float*)d_in[19];
  const float* dg2  = (const float*)d_in[20];
  const float* dbe2 = (const float*)d_in[21];
  const float* dtw2 = (const float*)d_in[22];
  const float* dtb2 = (const float*)d_in[23];

  char* wsb = (char*)d_ws;
  char* ob  = (char*)d_out;
  float* out = (float*)d_out;

  double* sums1 = (double*)(wsb + WS_SUMS + SUM1);
  double* sums2 = (double*)(wsb + WS_SUMS + SUM2);
  double* sums3 = (double*)(wsb + WS_SUMS + SUM3);
  double* sums4 = (double*)(wsb + WS_SUMS + SUM4);
  double* sums5 = (double*)(wsb + WS_SUMS + SUM5);
  float* y1 = (float*)(wsb + WS_Y1);
  float* y5 = (float*)(wsb + WS_Y5);
  float* y2 = (float*)(ob + DO_Y2);
  float* y3 = (float*)(ob + DO_Y3);
  float* y4 = (float*)(ob + DO_Y4);

  ae9_prep<<<1, 256, 0, stream>>>(w1, w2, w3, dw1, dtw1, dtw2, emb, wsb);
  aeF_conv1<<<1024, 256, 0, stream>>>(x, (const float*)(wsb + WS_W1T), b1, y1, sums1);
  ae9_conv2<<<512, 256, 0, stream>>>(y1, sums1, g1, be1, (const float*)(wsb + WS_W2T), b2, y2, sums2);
  ae9_conv3<<<512, 256, 0, stream>>>(y2, sums2, g2, be2, (const float*)(wsb + WS_W3T), b3, y3, sums3);
  aeG_vq<<<512, 256, 0, stream>>>(y3, sums3, g3, be3, emb, (const float*)(wsb + WS_E2F),
                                  (const float*)(wsb + WS_DW1T), db1, y4, sums4, out);
  aeF_dect1<<<1024, 256, 0, stream>>>(y4, sums4, dg1, dbe1, (const float*)(wsb + WS_DT1T), dtb1, y5, sums5);
  aeF_dect2<<<4096, 256, 0, stream>>>(y5, sums5, dg2, dbe2, (const float*)(wsb + WS_DT2T), dtb2, out);
}